// Round 1
// baseline (60.152 us; speedup 1.0000x reference)
//
#include <hip/hip_runtime.h>
#include <hip/hip_bf16.h>

#define N 4096
#define FIN 128
#define U0 16
#define H0 4
#define MAXD 128   // padded neighbor-list stride; P(deg>128) with Binom(4096,0.01) ~ 0

// ---------------------------------------------------------------------------
// K1: dense adj row -> padded CSR (deterministic, no global atomics)
// one block per row; coalesced float4 scan; LDS prefix-sum compaction
// ---------------------------------------------------------------------------
__global__ void build_csr(const float* __restrict__ adj,
                          int* __restrict__ deg, int* __restrict__ cols) {
    const int row = blockIdx.x;
    const int t = threadIdx.x;
    const float4* arow = reinterpret_cast<const float4*>(adj + (size_t)row * N);

    __shared__ int cnt[256];

    // pass 1: count nonzeros in this thread's 4 float4 chunks (coalesced)
    int c = 0;
    #pragma unroll
    for (int p = 0; p < 4; ++p) {
        float4 v = arow[t + 256 * p];
        c += (v.x != 0.f) + (v.y != 0.f) + (v.z != 0.f) + (v.w != 0.f);
    }
    cnt[t] = c;
    __syncthreads();

    // Hillis-Steele inclusive scan over 256 counts
    #pragma unroll
    for (int s = 1; s < 256; s <<= 1) {
        int v = (t >= s) ? cnt[t - s] : 0;
        __syncthreads();
        cnt[t] += v;
        __syncthreads();
    }
    int off = cnt[t] - c;          // exclusive prefix
    if (t == 255) deg[row] = min(cnt[255], MAXD);

    // pass 2: re-read (L1-hot) and write column indices in fixed order
    int w = row * MAXD + off;
    const int wend = row * MAXD + MAXD;
    #pragma unroll
    for (int p = 0; p < 4; ++p) {
        float4 v = arow[t + 256 * p];
        int j0 = (t + 256 * p) * 4;
        if (v.x != 0.f && w < wend) cols[w++] = j0;
        if (v.y != 0.f && w < wend) cols[w++] = j0 + 1;
        if (v.z != 0.f && w < wend) cols[w++] = j0 + 2;
        if (v.w != 0.f && w < wend) cols[w++] = j0 + 3;
    }
}

// ---------------------------------------------------------------------------
// K2: h0 = x @ w0 ([4096,128]@[128,16]), plus a1 = h0@aw1, a2 = h0@aw2
// block = 256 threads = 16 rows x 16 units
// ---------------------------------------------------------------------------
__global__ void gemm0(const float* __restrict__ x, const float* __restrict__ w0,
                      const float* __restrict__ aw1, const float* __restrict__ aw2,
                      float* __restrict__ h0, float* __restrict__ a1, float* __restrict__ a2) {
    __shared__ float xs[16][FIN + 1];   // +1 pad: break 16-way bank conflict
    __shared__ float ws[FIN][U0];
    __shared__ float hs[16][U0];
    const int t = threadIdx.x;
    const int r0 = blockIdx.x * 16;

    for (int k = t; k < FIN * U0; k += 256) ws[k / U0][k % U0] = w0[k];
    for (int k = t; k < 16 * FIN; k += 256)
        xs[k / FIN][k % FIN] = x[(size_t)(r0 + k / FIN) * FIN + (k % FIN)];
    __syncthreads();

    const int r = t / U0, u = t % U0;
    float acc = 0.f;
    #pragma unroll 8
    for (int k = 0; k < FIN; ++k) acc += xs[r][k] * ws[k][u];
    hs[r][u] = acc;
    h0[(size_t)(r0 + r) * U0 + u] = acc;
    __syncthreads();

    if (t < 16 * H0) {                 // 64 threads: (row, head)
        const int rr = t / H0, hh = t % H0;
        float s1 = 0.f, s2 = 0.f;
        #pragma unroll
        for (int u2 = 0; u2 < U0; ++u2) {
            float hv = hs[rr][u2];
            s1 += hv * aw1[u2 * H0 + hh];
            s2 += hv * aw2[u2 * H0 + hh];
        }
        a1[(r0 + rr) * H0 + hh] = s1;
        a2[(r0 + rr) * H0 + hh] = s2;
    }
}

// ---------------------------------------------------------------------------
// K2b: S0[d] = sum_j h0[j,d]   (16 blocks, one per column)
// ---------------------------------------------------------------------------
__global__ void colsum0(const float* __restrict__ h0, float* __restrict__ S0) {
    const int d = blockIdx.x, t = threadIdx.x;
    __shared__ float part[4];
    float s = 0.f;
    for (int j = t; j < N; j += 256) s += h0[(size_t)j * U0 + d];
    #pragma unroll
    for (int o = 32; o; o >>= 1) s += __shfl_down(s, o);
    if ((t & 63) == 0) part[t >> 6] = s;
    __syncthreads();
    if (t == 0) S0[d] = part[0] + part[1] + part[2] + part[3];
}

// ---------------------------------------------------------------------------
// K3: layer-0 sparse attention + relu -> h1 [4096, 64]
// 4 rows per block; 64 threads per row: t = hh*16 + d
// ---------------------------------------------------------------------------
__global__ void attn0(const float* __restrict__ h0, const float* __restrict__ a1,
                      const float* __restrict__ a2, const float* __restrict__ S0,
                      const int* __restrict__ deg, const int* __restrict__ cols,
                      float* __restrict__ h1) {
    const int i = blockIdx.x * 4 + (threadIdx.x >> 6);
    const int t = threadIdx.x & 63;
    const int hh = t >> 4, d = t & 15;

    const float a1v = a1[i * H0 + hh];
    const int dg = deg[i];
    const int* __restrict__ cl = cols + (size_t)i * MAXD;

    float accn = 0.f, accd = 0.f;
    for (int k = 0; k < dg; ++k) {
        const int j = cl[k];                       // wave-uniform broadcast
        float c = a1v + a2[j * H0 + hh];
        c = c > 0.f ? c : 0.f;
        const float e = __expf(c) - 1.f;
        accn = fmaf(e, h0[(size_t)j * U0 + d], accn);
        accd += e;
    }
    const float o = (accn + S0[d]) / (accd + (float)N);
    h1[(size_t)i * 64 + hh * U0 + d] = o > 0.f ? o : 0.f;   // relu activation
}

// ---------------------------------------------------------------------------
// K4: hp = h1 @ w1  ([4096,64]@[64,1])
// ---------------------------------------------------------------------------
__global__ void gemm1(const float* __restrict__ h1, const float* __restrict__ w1,
                      float* __restrict__ hp) {
    __shared__ float wl[64];
    const int t = threadIdx.x;
    if (t < 64) wl[t] = w1[t];
    __syncthreads();
    const int i = blockIdx.x * 256 + t;
    const float4* hr = reinterpret_cast<const float4*>(h1 + (size_t)i * 64);
    float s = 0.f;
    #pragma unroll
    for (int k = 0; k < 16; ++k) {
        float4 v = hr[k];
        s += v.x * wl[4 * k] + v.y * wl[4 * k + 1] + v.z * wl[4 * k + 2] + v.w * wl[4 * k + 3];
    }
    hp[i] = s;
}

// ---------------------------------------------------------------------------
// K4b: S1 = sum_j hp[j]
// ---------------------------------------------------------------------------
__global__ void colsum1(const float* __restrict__ hp, float* __restrict__ S1) {
    const int t = threadIdx.x;
    __shared__ float part[4];
    float s = 0.f;
    for (int j = t; j < N; j += 256) s += hp[j];
    #pragma unroll
    for (int o = 32; o; o >>= 1) s += __shfl_down(s, o);
    if ((t & 63) == 0) part[t >> 6] = s;
    __syncthreads();
    if (t == 0) S1[0] = part[0] + part[1] + part[2] + part[3];
}

// ---------------------------------------------------------------------------
// K5: layer-1 sparse attention (scalar feature) + sigmoid -> out [4096]
// one wave per row, 4 rows per block
// ---------------------------------------------------------------------------
__global__ void attn1(const float* __restrict__ hp, const float* __restrict__ S1,
                      const float* __restrict__ aw11, const float* __restrict__ aw21,
                      const int* __restrict__ deg, const int* __restrict__ cols,
                      float* __restrict__ out) {
    const int i = blockIdx.x * 4 + (threadIdx.x >> 6);
    const int lane = threadIdx.x & 63;
    const float w1v = aw11[0], w2v = aw21[0];
    const float a1v = hp[i] * w1v;
    const int dg = deg[i];
    const int* __restrict__ cl = cols + (size_t)i * MAXD;

    float accn = 0.f, accd = 0.f;
    for (int k = lane; k < dg; k += 64) {
        const int j = cl[k];
        const float hj = hp[j];
        float c = a1v + hj * w2v;
        c = c > 0.f ? c : 0.f;
        const float e = __expf(c) - 1.f;
        accn = fmaf(e, hj, accn);
        accd += e;
    }
    #pragma unroll
    for (int o = 32; o; o >>= 1) {
        accn += __shfl_down(accn, o);
        accd += __shfl_down(accd, o);
    }
    if (lane == 0) {
        const float v = (accn + S1[0]) / (accd + (float)N);
        out[i] = 1.f / (1.f + __expf(-v));
    }
}

// ---------------------------------------------------------------------------
extern "C" void kernel_launch(void* const* d_in, const int* in_sizes, int n_in,
                              void* d_out, int out_size, void* d_ws, size_t ws_size,
                              hipStream_t stream) {
    const float* x    = (const float*)d_in[0];
    const float* adj  = (const float*)d_in[1];
    const float* w0   = (const float*)d_in[2];
    const float* aw10 = (const float*)d_in[3];
    const float* aw20 = (const float*)d_in[4];
    const float* w1   = (const float*)d_in[5];
    const float* aw11 = (const float*)d_in[6];
    const float* aw21 = (const float*)d_in[7];
    float* out = (float*)d_out;

    char* p = (char*)d_ws;
    auto alloc = [&](size_t bytes) {
        char* r = p;
        p += (bytes + 255) & ~(size_t)255;
        return r;
    };
    float* h0  = (float*)alloc((size_t)N * U0 * 4);
    float* a1  = (float*)alloc((size_t)N * H0 * 4);
    float* a2  = (float*)alloc((size_t)N * H0 * 4);
    float* S0  = (float*)alloc(U0 * 4);
    float* h1  = (float*)alloc((size_t)N * 64 * 4);
    float* hp  = (float*)alloc((size_t)N * 4);
    float* S1  = (float*)alloc(64);
    int*   deg = (int*)alloc((size_t)N * 4);
    int*   cols= (int*)alloc((size_t)N * MAXD * 4);

    build_csr<<<N, 256, 0, stream>>>(adj, deg, cols);
    gemm0<<<N / 16, 256, 0, stream>>>(x, w0, aw10, aw20, h0, a1, a2);
    colsum0<<<U0, 256, 0, stream>>>(h0, S0);
    attn0<<<N / 4, 256, 0, stream>>>(h0, a1, a2, S0, deg, cols, h1);
    gemm1<<<N / 256, 256, 0, stream>>>(h1, w1, hp);
    colsum1<<<1, 256, 0, stream>>>(hp, S1);
    attn1<<<N / 4, 256, 0, stream>>>(hp, S1, aw11, aw21, deg, cols, out);
}

// Round 2
// 53.243 us; speedup vs baseline: 1.1298x; 1.1298x over previous
//
#include <hip/hip_runtime.h>
#include <hip/hip_bf16.h>

#define N 4096
#define FIN 128
#define U0 16
#define H0 4
#define MAXD 128   // padded neighbor-list stride; P(deg>128), Binom(4096,0.01) ~ 0

// ---------------------------------------------------------------------------
// K1: dense adj row -> padded CSR. Single pass (row in registers),
// wave-level shfl scan + one barrier (vs 16-barrier LDS scan).
// ---------------------------------------------------------------------------
__global__ void build_csr(const float* __restrict__ adj,
                          int* __restrict__ deg, int* __restrict__ cols) {
    const int row = blockIdx.x;
    const int t = threadIdx.x;
    const int lane = t & 63, wid = t >> 6;
    const float4* __restrict__ arow = reinterpret_cast<const float4*>(adj + (size_t)row * N);

    float4 v[4];
    int c = 0;
    #pragma unroll
    for (int p = 0; p < 4; ++p) {
        v[p] = arow[t + 256 * p];
        c += (v[p].x != 0.f) + (v[p].y != 0.f) + (v[p].z != 0.f) + (v[p].w != 0.f);
    }

    // inclusive scan within 64-lane wave (6 shfl steps, no barriers)
    int sc = c;
    #pragma unroll
    for (int s = 1; s < 64; s <<= 1) {
        int u = __shfl_up(sc, s);
        if (lane >= s) sc += u;
    }
    __shared__ int wsum[4];
    if (lane == 63) wsum[wid] = sc;
    __syncthreads();
    int base = 0;
    #pragma unroll
    for (int w2 = 0; w2 < 4; ++w2)
        if (w2 < wid) base += wsum[w2];
    const int off = base + sc - c;          // exclusive prefix across 256 threads
    if (t == 255) deg[row] = min(base + sc, MAXD);

    int w = row * MAXD + off;
    const int wend = row * MAXD + MAXD;
    #pragma unroll
    for (int p = 0; p < 4; ++p) {
        const int j0 = (t + 256 * p) * 4;
        if (v[p].x != 0.f && w < wend) cols[w++] = j0;
        if (v[p].y != 0.f && w < wend) cols[w++] = j0 + 1;
        if (v[p].z != 0.f && w < wend) cols[w++] = j0 + 2;
        if (v[p].w != 0.f && w < wend) cols[w++] = j0 + 3;
    }
}

// ---------------------------------------------------------------------------
// K2: h0 = x @ w0, a1 = h0@aw1, a2 = h0@aw2, + per-block column partials of h0
// block = 256 threads = 16 rows x 16 units
// ---------------------------------------------------------------------------
__global__ void gemm0(const float* __restrict__ x, const float* __restrict__ w0,
                      const float* __restrict__ aw1, const float* __restrict__ aw2,
                      float* __restrict__ h0, float* __restrict__ a1, float* __restrict__ a2,
                      float* __restrict__ partS0 /* [N/16][16] */) {
    __shared__ float xs[16][FIN + 1];
    __shared__ float ws[FIN][U0];
    __shared__ float hs[16][U0 + 1];
    const int t = threadIdx.x;
    const int r0 = blockIdx.x * 16;

    for (int k = t; k < FIN * U0; k += 256) ws[k / U0][k % U0] = w0[k];
    for (int k = t; k < 16 * FIN; k += 256)
        xs[k / FIN][k % FIN] = x[(size_t)(r0 + k / FIN) * FIN + (k % FIN)];
    __syncthreads();

    const int r = t / U0, u = t % U0;
    float acc = 0.f;
    #pragma unroll 8
    for (int k = 0; k < FIN; ++k) acc += xs[r][k] * ws[k][u];
    hs[r][u] = acc;
    h0[(size_t)(r0 + r) * U0 + u] = acc;
    __syncthreads();

    if (t < 16 * H0) {                 // 64 threads: (row, head)
        const int rr = t / H0, hh = t % H0;
        float s1 = 0.f, s2 = 0.f;
        #pragma unroll
        for (int u2 = 0; u2 < U0; ++u2) {
            float hv = hs[rr][u2];
            s1 += hv * aw1[u2 * H0 + hh];
            s2 += hv * aw2[u2 * H0 + hh];
        }
        a1[(r0 + rr) * H0 + hh] = s1;
        a2[(r0 + rr) * H0 + hh] = s2;
    } else if (t >= 128 && t < 144) {  // 16 threads: per-block column partial
        const int d = t - 128;
        float s = 0.f;
        #pragma unroll
        for (int rr = 0; rr < 16; ++rr) s += hs[rr][d];
        partS0[blockIdx.x * 16 + d] = s;
    }
}

// ---------------------------------------------------------------------------
// K3: layer-0 sparse attention + relu, fused with hp = h1@w1 and S1 partials.
// h1 never hits global memory. 4 rows/block; 64 threads/row: t = hh*16 + d.
// ---------------------------------------------------------------------------
__global__ void attn0(const float* __restrict__ h0, const float* __restrict__ a1,
                      const float* __restrict__ a2, const float* __restrict__ partS0,
                      const int* __restrict__ deg, const int* __restrict__ cols,
                      const float* __restrict__ w1,
                      float* __restrict__ hp, float* __restrict__ partS1) {
    __shared__ float red[16][17];
    __shared__ float s0s[16];
    __shared__ float rowv[4];
    const int t = threadIdx.x;

    // reduce partS0 [256][16] -> S0[16] (redundant per block; L2-hot)
    {
        const int d = t & 15, ch = t >> 4;
        float s = 0.f;
        #pragma unroll
        for (int k = ch; k < 256; k += 16) s += partS0[k * 16 + d];
        red[ch][d] = s;
        __syncthreads();
        if (t < 16) {
            float s2 = 0.f;
            #pragma unroll
            for (int k = 0; k < 16; ++k) s2 += red[k][t];
            s0s[t] = s2;
        }
        __syncthreads();
    }

    const int i = blockIdx.x * 4 + (t >> 6);
    const int lane = t & 63;
    const int hh = lane >> 4, d = lane & 15;

    const float a1v = a1[i * H0 + hh];
    const int dg = deg[i];
    const int* __restrict__ cl = cols + (size_t)i * MAXD;

    float accn = 0.f, accd = 0.f;
    for (int k = 0; k < dg; ++k) {
        const int j = cl[k];
        float c = a1v + a2[j * H0 + hh];
        c = c > 0.f ? c : 0.f;
        const float e = __expf(c) - 1.f;
        accn = fmaf(e, h0[(size_t)j * U0 + d], accn);
        accd += e;
    }
    float o = (accn + s0s[d]) / (accd + (float)N);
    o = o > 0.f ? o : 0.f;                       // relu -> h1[i, hh*16+d]

    // hp[i] = sum_{hd} h1[i,hd] * w1[hd]  (64-lane wave reduce)
    float pv = o * w1[hh * U0 + d];
    #pragma unroll
    for (int off = 32; off; off >>= 1) pv += __shfl_down(pv, off);
    if (lane == 0) {
        hp[i] = pv;
        rowv[t >> 6] = pv;
    }
    __syncthreads();
    if (t == 0) partS1[blockIdx.x] = rowv[0] + rowv[1] + rowv[2] + rowv[3];
}

// ---------------------------------------------------------------------------
// K4: layer-1 sparse attention (scalar feature) + sigmoid -> out [4096]
// reduces partS1 [1024] per block, then one wave per row, 4 rows/block
// ---------------------------------------------------------------------------
__global__ void attn1(const float* __restrict__ hp, const float* __restrict__ partS1,
                      const float* __restrict__ aw11, const float* __restrict__ aw21,
                      const int* __restrict__ deg, const int* __restrict__ cols,
                      float* __restrict__ out) {
    const int t = threadIdx.x;
    __shared__ float red2[4];
    __shared__ float s1sh;
    {
        float s = 0.f;
        #pragma unroll
        for (int k = t; k < 1024; k += 256) s += partS1[k];
        #pragma unroll
        for (int o = 32; o; o >>= 1) s += __shfl_down(s, o);
        if ((t & 63) == 0) red2[t >> 6] = s;
        __syncthreads();
        if (t == 0) s1sh = red2[0] + red2[1] + red2[2] + red2[3];
        __syncthreads();
    }
    const float S1 = s1sh;

    const int i = blockIdx.x * 4 + (t >> 6);
    const int lane = t & 63;
    const float w1v = aw11[0], w2v = aw21[0];
    const float a1v = hp[i] * w1v;
    const int dg = deg[i];
    const int* __restrict__ cl = cols + (size_t)i * MAXD;

    float accn = 0.f, accd = 0.f;
    for (int k = lane; k < dg; k += 64) {
        const int j = cl[k];
        const float hj = hp[j];
        float c = a1v + hj * w2v;
        c = c > 0.f ? c : 0.f;
        const float e = __expf(c) - 1.f;
        accn = fmaf(e, hj, accn);
        accd += e;
    }
    #pragma unroll
    for (int o = 32; o; o >>= 1) {
        accn += __shfl_down(accn, o);
        accd += __shfl_down(accd, o);
    }
    if (lane == 0) {
        const float v = (accn + S1) / (accd + (float)N);
        out[i] = 1.f / (1.f + __expf(-v));
    }
}

// ---------------------------------------------------------------------------
extern "C" void kernel_launch(void* const* d_in, const int* in_sizes, int n_in,
                              void* d_out, int out_size, void* d_ws, size_t ws_size,
                              hipStream_t stream) {
    const float* x    = (const float*)d_in[0];
    const float* adj  = (const float*)d_in[1];
    const float* w0   = (const float*)d_in[2];
    const float* aw10 = (const float*)d_in[3];
    const float* aw20 = (const float*)d_in[4];
    const float* w1   = (const float*)d_in[5];
    const float* aw11 = (const float*)d_in[6];
    const float* aw21 = (const float*)d_in[7];
    float* out = (float*)d_out;

    char* p = (char*)d_ws;
    auto alloc = [&](size_t bytes) {
        char* r = p;
        p += (bytes + 255) & ~(size_t)255;
        return r;
    };
    float* h0     = (float*)alloc((size_t)N * U0 * 4);
    float* a1     = (float*)alloc((size_t)N * H0 * 4);
    float* a2     = (float*)alloc((size_t)N * H0 * 4);
    float* partS0 = (float*)alloc((size_t)(N / 16) * 16 * 4);
    float* hp     = (float*)alloc((size_t)N * 4);
    float* partS1 = (float*)alloc((size_t)(N / 4) * 4);
    int*   deg    = (int*)alloc((size_t)N * 4);
    int*   cols   = (int*)alloc((size_t)N * MAXD * 4);

    build_csr<<<N, 256, 0, stream>>>(adj, deg, cols);
    gemm0<<<N / 16, 256, 0, stream>>>(x, w0, aw10, aw20, h0, a1, a2, partS0);
    attn0<<<N / 4, 256, 0, stream>>>(h0, a1, a2, partS0, deg, cols, w1, hp, partS1);
    attn1<<<N / 4, 256, 0, stream>>>(hp, partS1, aw11, aw21, deg, cols, out);
}